// Round 4
// baseline (515.502 us; speedup 1.0000x reference)
//
#include <hip/hip_runtime.h>
#include <math.h>

#define DIM_    128
#define QH_     16
#define KVH_    4
#define WIN_    512
#define BATCH_  4
#define SEQ_    2048
#define QKV_LD  3072
#define ATT_LD  2048

#define NX   (BATCH_*SEQ_*DIM_)   // 1048576
#define NWQ  (DIM_*QKV_LD)        // 393216
#define NWP  (ATT_LD*DIM_)        // 262144

typedef __attribute__((ext_vector_type(8))) short short8;
typedef __attribute__((ext_vector_type(4))) float f32x4;
typedef unsigned short u16;
typedef unsigned int u32;

__device__ __forceinline__ u16 f2bf(float f) {        // RNE, finite inputs
    u32 u = __float_as_uint(f);
    u += 0x7fff + ((u >> 16) & 1);
    return (u16)(u >> 16);
}
__device__ __forceinline__ float bf2f(u16 u) {
    return __uint_as_float(((u32)u) << 16);
}
#define MFMA16 __builtin_amdgcn_mfma_f32_16x16x32_bf16

// ---------- convert: x -> (xh,xl) row-major; Wqkv -> Wt (3072x128) h/l;
//            Wproj -> Wpt (128x2048) h/l.  Split bf16 pairs for ~fp32 GEMMs.
__global__ __launch_bounds__(256) void convert_inputs(
    const float* __restrict__ x, const float* __restrict__ Wqkv,
    const float* __restrict__ Wproj,
    u16* __restrict__ xh, u16* __restrict__ xl,
    u16* __restrict__ wth, u16* __restrict__ wtl,
    u16* __restrict__ wpth, u16* __restrict__ wptl)
{
    const int t = blockIdx.x * 256 + threadIdx.x;
    float v; u16 *dh, *dl; int idx;
    if (t < NX) {
        v = x[t]; dh = xh; dl = xl; idx = t;
    } else if (t < NX + NWQ) {
        const int u2 = t - NX;
        const int k = u2 & 127, n = u2 >> 7;          // Wt[n][k] = Wqkv[k][n]
        v = Wqkv[(size_t)k * QKV_LD + n]; dh = wth; dl = wtl; idx = u2;
    } else {
        const int u2 = t - NX - NWQ;
        const int k = u2 & 2047, n = u2 >> 11;        // Wpt[n][k] = Wproj[k][n]
        v = Wproj[(size_t)k * DIM_ + n]; dh = wpth; dl = wptl; idx = u2;
    }
    const u16 h = f2bf(v);
    dh[idx] = h;
    dl[idx] = f2bf(v - bf2f(h));
}

// ---------- GEMM1 (MFMA, split bf16): qkv = x @ Wqkv.
// Block 64x64, wave w owns 16 rows. Q/K cols -> qkvb[8192][3072] bf16;
// V cols -> vg[b][kvh][d][seq] bf16 (each block fills whole 128B lines).
__global__ __launch_bounds__(256) void gemm1_mfma(
    const u16* __restrict__ xh, const u16* __restrict__ xl,
    const u16* __restrict__ wth, const u16* __restrict__ wtl,
    u16* __restrict__ qkvb, u16* __restrict__ vg)
{
    const int bn = blockIdx.x * 64;
    const int wv = threadIdx.x >> 6, lane = threadIdx.x & 63;
    const int lr = lane & 15, quad = lane >> 4;
    const int bm = blockIdx.y * 64 + wv * 16;

    short8 af_h[4], af_l[4];
    {
        const u16* ap  = xh + (size_t)(bm + lr) * DIM_ + quad * 8;
        const u16* alp = xl + (size_t)(bm + lr) * DIM_ + quad * 8;
        #pragma unroll
        for (int s = 0; s < 4; ++s) {
            af_h[s] = *(const short8*)(ap + 32 * s);
            af_l[s] = *(const short8*)(alp + 32 * s);
        }
    }

    #pragma unroll
    for (int nt = 0; nt < 4; ++nt) {
        const int n0 = bn + nt * 16;
        const u16* bp  = wth + (size_t)(n0 + lr) * DIM_ + quad * 8;
        const u16* blp = wtl + (size_t)(n0 + lr) * DIM_ + quad * 8;
        f32x4 c1 = {0.f, 0.f, 0.f, 0.f}, c2 = {0.f, 0.f, 0.f, 0.f};
        #pragma unroll
        for (int s = 0; s < 4; ++s) {
            short8 bh = *(const short8*)(bp + 32 * s);
            short8 bl = *(const short8*)(blp + 32 * s);
            c1 = MFMA16(af_h[s], bh, c1, 0, 0, 0);
            c2 = MFMA16(af_l[s], bh, c2, 0, 0, 0);
            c2 = MFMA16(af_h[s], bl, c2, 0, 0, 0);
        }
        if (bn < 2560) {                       // Q/K region (block-uniform)
            #pragma unroll
            for (int r = 0; r < 4; ++r)
                qkvb[(size_t)(bm + quad * 4 + r) * QKV_LD + n0 + lr] =
                    f2bf(c1[r] + c2[r]);
        } else {                               // V region -> transposed vg
            const int ncol = n0 + lr - 2560;
            const int kvh = ncol >> 7, d = ncol & 127;
            #pragma unroll
            for (int r = 0; r < 4; ++r) {
                const int m = bm + quad * 4 + r;
                vg[((size_t)((m >> 11) * KVH_ + kvh) * DIM_ + d) * SEQ_ + (m & 2047)] =
                    f2bf(c1[r] + c2[r]);
            }
        }
    }
}

// ---------- MFMA attention, fused-exp softmax, 1 barrier -------------------
// exp2-domain with fixed per-row shift slope*min(q,WIN) (shift-invariant,
// no overflow: residual <= ~7). Row sums accumulated in registers during QK,
// reduced by 16-wide shuffles -> no separate softmax phase.
__global__ __launch_bounds__(256) void attn_mfma(
    const u16* __restrict__ qkvb, const u16* __restrict__ vg,
    u16* __restrict__ ah, u16* __restrict__ al)
{
    const int qt = blockIdx.x, h = blockIdx.y, b = blockIdx.z;
    const int q0 = qt << 4;
    const int tid = threadIdx.x;
    const int wv = tid >> 6, lane = tid & 63;
    const int lr = lane & 15, quad = lane >> 4;

    __shared__ __align__(16) u16 Sc[16][568];   // bf16 P; stride 1136B
    __shared__ __align__(16) float red[16][4];  // per-wave row-sum partials

    const int   kvh    = h >> 2;
    const float scale2 = 0.08838834764831845f * 1.4426950408889634f; // /sqrt(d)*log2e
    const float slope2 = exp2f(-0.5f * (float)(h + 1)) * 1.4426950408889634f;
    const int   jbase  = max(0, q0 - WIN_);
    const int   nkey   = q0 + 16 - jbase;       // multiple of 16, <=528
    const int   nchunk = nkey >> 4;
    const int   nslice = (nchunk + 1) >> 1;
    const int   jend   = q0 + 16;
    const size_t rowb  = (size_t)b * SEQ_;

    // Q A-frags in regs
    short8 qf[4];
    {
        const u16* qp = qkvb + (rowb + q0 + lr) * QKV_LD + h * DIM_ + quad * 8;
        qf[0] = *(const short8*)(qp);
        qf[1] = *(const short8*)(qp + 32);
        qf[2] = *(const short8*)(qp + 64);
        qf[3] = *(const short8*)(qp + 96);
    }

    // ---- QK^T with software-pipelined global K loads + fused exp + reg sums
    float rs[4] = {0.f, 0.f, 0.f, 0.f};
    int ch = wv;
    short8 k0, k1, k2, k3, n0, n1, n2, n3;
    if (ch < nchunk) {
        const u16* kp = qkvb + (rowb + jbase + (ch << 4) + lr) * QKV_LD
                        + (QH_ + kvh) * DIM_ + quad * 8;
        k0 = *(const short8*)(kp);      k1 = *(const short8*)(kp + 32);
        k2 = *(const short8*)(kp + 64); k3 = *(const short8*)(kp + 96);
    }
    while (ch < nchunk) {
        const int nc = ch + 4;
        if (nc < nchunk) {
            const u16* kp = qkvb + (rowb + jbase + (nc << 4) + lr) * QKV_LD
                            + (QH_ + kvh) * DIM_ + quad * 8;
            n0 = *(const short8*)(kp);      n1 = *(const short8*)(kp + 32);
            n2 = *(const short8*)(kp + 64); n3 = *(const short8*)(kp + 96);
        }
        f32x4 c = {0.f, 0.f, 0.f, 0.f};
        c = MFMA16(qf[0], k0, c, 0, 0, 0);
        c = MFMA16(qf[1], k1, c, 0, 0, 0);
        c = MFMA16(qf[2], k2, c, 0, 0, 0);
        c = MFMA16(qf[3], k3, c, 0, 0, 0);
        const int j = jbase + (ch << 4) + lr;
        #pragma unroll
        for (int r = 0; r < 4; ++r) {
            const int q = q0 + quad * 4 + r;             // C row = quad*4+r
            const int rel = q - j;
            const int relmax = (q < WIN_) ? q : WIN_;
            float e = 0.f;
            if (rel >= 0 && rel <= WIN_)
                e = exp2f(fmaf(c[r], scale2, slope2 * (float)(rel - relmax)));
            Sc[quad * 4 + r][(ch << 4) + lr] = f2bf(e);
            rs[r] += e;
        }
        k0 = n0; k1 = n1; k2 = n2; k3 = n3;
        ch = nc;
    }
    #pragma unroll
    for (int o = 1; o < 16; o <<= 1) {
        #pragma unroll
        for (int r = 0; r < 4; ++r) rs[r] += __shfl_xor(rs[r], o, 16);
    }
    if (lr == 0) {
        #pragma unroll
        for (int r = 0; r < 4; ++r) red[quad * 4 + r][wv] = rs[r];
    }
    if (nchunk & 1) Sc[tid >> 4][nkey + (tid & 15)] = 0;   // zero pad for PV
    __syncthreads();

    // ---- P @ V, software-pipelined; wave owns dims [32w,32w+32)
    f32x4 o0 = {0.f, 0.f, 0.f, 0.f}, o1 = {0.f, 0.f, 0.f, 0.f};
    const u16* vb = vg + ((size_t)(b * KVH_ + kvh) * DIM_ + wv * 32 + lr) * SEQ_;
    short8 pa, v0, v1, pan, v0n, v1n;
    {
        const int jc = quad * 8;
        pa = *(const short8*)&Sc[lr][jc];
        int jg = jbase + jc; if (jg >= jend) jg = jbase;    // pad cols: P=0
        v0 = *(const short8*)(vb + jg);
        v1 = *(const short8*)(vb + (size_t)16 * SEQ_ + jg);
    }
    for (int sl = 0; sl < nslice; ++sl) {
        if (sl + 1 < nslice) {
            const int jc = ((sl + 1) << 5) + quad * 8;
            pan = *(const short8*)&Sc[lr][jc];
            int jg = jbase + jc; if (jg >= jend) jg = jbase;
            v0n = *(const short8*)(vb + jg);
            v1n = *(const short8*)(vb + (size_t)16 * SEQ_ + jg);
        }
        o0 = MFMA16(pa, v0, o0, 0, 0, 0);
        o1 = MFMA16(pa, v1, o1, 0, 0, 0);
        pa = pan; v0 = v0n; v1 = v1n;
    }

    // ---- epilogue: 1/sum, write att as split bf16 (ah + al)
    #pragma unroll
    for (int r = 0; r < 4; ++r) {
        const int row = quad * 4 + r;
        f32x4 t = *(const f32x4*)&red[row][0];
        const float inv = 1.0f / (t[0] + t[1] + t[2] + t[3]);
        const size_t idx = (rowb + q0 + row) * (size_t)ATT_LD + h * DIM_ + wv * 32 + lr;
        float v0o = o0[r] * inv;
        u16 hh = f2bf(v0o);
        ah[idx] = hh; al[idx] = f2bf(v0o - bf2f(hh));
        float v1o = o1[r] * inv;
        hh = f2bf(v1o);
        ah[idx + 16] = hh; al[idx + 16] = f2bf(v1o - bf2f(hh));
    }
}

// ---------- GEMM2 (MFMA, split bf16): out = att @ Wproj, fp32 out ----------
// Block = 16 rows, 4 waves each own 32 of the 128 cols; K=2048 pipelined.
__global__ __launch_bounds__(256) void gemm2_mfma(
    const u16* __restrict__ ah, const u16* __restrict__ al,
    const u16* __restrict__ wpth, const u16* __restrict__ wptl,
    float* __restrict__ out)
{
    const int bm = blockIdx.x * 16;
    const int wv = threadIdx.x >> 6, lane = threadIdx.x & 63;
    const int lr = lane & 15, quad = lane >> 4;
    const int nb = wv * 32;

    const u16* a0  = ah   + (size_t)(bm + lr) * ATT_LD + quad * 8;
    const u16* a1  = al   + (size_t)(bm + lr) * ATT_LD + quad * 8;
    const u16* b0h = wpth + (size_t)(nb + lr) * ATT_LD + quad * 8;
    const u16* b0l = wptl + (size_t)(nb + lr) * ATT_LD + quad * 8;
    const u16* b1h = b0h + (size_t)16 * ATT_LD;
    const u16* b1l = b0l + (size_t)16 * ATT_LD;

    f32x4 c1a = {0.f,0.f,0.f,0.f}, c2a = {0.f,0.f,0.f,0.f};
    f32x4 c1b = {0.f,0.f,0.f,0.f}, c2b = {0.f,0.f,0.f,0.f};

    short8 Ah, Al, B0h, B0l, B1h, B1l;
    short8 nAh, nAl, nB0h, nB0l, nB1h, nB1l;
    Ah  = *(const short8*)(a0);  Al  = *(const short8*)(a1);
    B0h = *(const short8*)(b0h); B0l = *(const short8*)(b0l);
    B1h = *(const short8*)(b1h); B1l = *(const short8*)(b1l);
    for (int k0 = 0; k0 < ATT_LD; k0 += 32) {
        const int kn = k0 + 32;
        if (kn < ATT_LD) {
            nAh  = *(const short8*)(a0 + kn);  nAl  = *(const short8*)(a1 + kn);
            nB0h = *(const short8*)(b0h + kn); nB0l = *(const short8*)(b0l + kn);
            nB1h = *(const short8*)(b1h + kn); nB1l = *(const short8*)(b1l + kn);
        }
        c1a = MFMA16(Ah, B0h, c1a, 0, 0, 0);
        c2a = MFMA16(Al, B0h, c2a, 0, 0, 0);
        c2a = MFMA16(Ah, B0l, c2a, 0, 0, 0);
        c1b = MFMA16(Ah, B1h, c1b, 0, 0, 0);
        c2b = MFMA16(Al, B1h, c2b, 0, 0, 0);
        c2b = MFMA16(Ah, B1l, c2b, 0, 0, 0);
        Ah = nAh; Al = nAl; B0h = nB0h; B0l = nB0l; B1h = nB1h; B1l = nB1l;
    }
    #pragma unroll
    for (int r = 0; r < 4; ++r) {
        const size_t rofs = (size_t)(bm + quad * 4 + r) * DIM_;
        out[rofs + nb + lr]      = c1a[r] + c2a[r];
        out[rofs + nb + 16 + lr] = c1b[r] + c2b[r];
    }
}

// ---------- launch ----------------------------------------------------------
extern "C" void kernel_launch(void* const* d_in, const int* in_sizes, int n_in,
                              void* d_out, int out_size, void* d_ws, size_t ws_size,
                              hipStream_t stream)
{
    const float* x     = (const float*)d_in[0];
    const float* Wqkv  = (const float*)d_in[1];
    const float* Wproj = (const float*)d_in[2];
    float* out = (float*)d_out;

    u16* xh   = (u16*)d_ws;            // sizes in u16 elements
    u16* xl   = xh   + (size_t)NX;
    u16* wth  = xl   + (size_t)NX;
    u16* wtl  = wth  + (size_t)NWQ;
    u16* wpth = wtl  + (size_t)NWQ;
    u16* wptl = wpth + (size_t)NWP;
    u16* qkvb = wptl + (size_t)NWP;                       // 8192*3072
    u16* vg   = qkvb + (size_t)8192 * QKV_LD;             // 4*4*128*2048
    u16* ahp  = vg   + (size_t)BATCH_ * KVH_ * DIM_ * SEQ_; // 8192*2048
    u16* alp  = ahp  + (size_t)8192 * ATT_LD;

    const dim3 blk(256);

    convert_inputs<<<(NX + NWQ + NWP) / 256, blk, 0, stream>>>(
        x, Wqkv, Wproj, xh, xl, wth, wtl, wpth, wptl);

    gemm1_mfma<<<dim3(QKV_LD / 64, 8192 / 64), blk, 0, stream>>>(
        xh, xl, wth, wtl, qkvb, vg);

    attn_mfma<<<dim3(SEQ_ / 16, QH_, BATCH_), blk, 0, stream>>>(qkvb, vg, ahp, alp);

    gemm2_mfma<<<8192 / 16, blk, 0, stream>>>(ahp, alp, wpth, wptl, out);
}

// Round 5
// 240.484 us; speedup vs baseline: 2.1436x; 2.1436x over previous
//
#include <hip/hip_runtime.h>
#include <math.h>

#define DIM_    128
#define QH_     16
#define KVH_    4
#define WIN_    512
#define BATCH_  4
#define SEQ_    2048
#define QKV_LD  3072
#define ATT_LD  2048

#define NX   (BATCH_*SEQ_*DIM_)   // 1048576
#define NWQ  (DIM_*QKV_LD)        // 393216
#define NWP  (ATT_LD*DIM_)        // 262144

typedef __attribute__((ext_vector_type(8))) short short8;
typedef __attribute__((ext_vector_type(4))) float f32x4;
typedef unsigned short u16;
typedef unsigned int u32;

__device__ __forceinline__ u16 f2bf(float f) {
    u32 u = __float_as_uint(f);
    u += 0x7fff + ((u >> 16) & 1);
    return (u16)(u >> 16);
}
__device__ __forceinline__ float bf2f(u16 u) {
    return __uint_as_float(((u32)u) << 16);
}
#define MFMA16 __builtin_amdgcn_mfma_f32_16x16x32_bf16

// global -> LDS direct (16B/lane, lds dst = wave-uniform base + lane*16)
__device__ __forceinline__ void gload_lds16(const u16* g, u16* l) {
    __builtin_amdgcn_global_load_lds(
        (const __attribute__((address_space(1))) unsigned int*)(const void*)g,
        (__attribute__((address_space(3))) unsigned int*)(void*)l, 16, 0, 0);
}

// ---------- convert: xh = bf16(x); wth = bf16(Wqkv^T) [3072][128];
//            wpth/wptl = split bf16(Wproj^T) [128][2048]
__global__ __launch_bounds__(256) void convert_inputs(
    const float* __restrict__ x, const float* __restrict__ Wqkv,
    const float* __restrict__ Wproj,
    u16* __restrict__ xh, u16* __restrict__ wth,
    u16* __restrict__ wpth, u16* __restrict__ wptl)
{
    const int t = blockIdx.x * 256 + threadIdx.x;
    if (t < NX) {
        xh[t] = f2bf(x[t]);
    } else if (t < NX + NWQ) {
        const int u2 = t - NX;
        const int k = u2 & 127, n = u2 >> 7;
        wth[u2] = f2bf(Wqkv[(size_t)k * QKV_LD + n]);
    } else {
        const int u2 = t - NX - NWQ;
        const int k = u2 & 2047, n = u2 >> 11;
        const float v = Wproj[(size_t)k * DIM_ + n];
        const u16 h = f2bf(v);
        wpth[u2] = h;
        wptl[u2] = f2bf(v - bf2f(h));
    }
}

// ---------- GEMM1 (bf16 MFMA, LDS-tiled): qkv = x @ Wqkv -------------------
// Block 128(M) x 64(N), K=128 one-shot. Q/K cols -> qkvb[8192][3072];
// V cols (n>=2560) -> vg[b][kvh][d][seq].
__global__ __launch_bounds__(256) void gemm1_mfma(
    const u16* __restrict__ xh, const u16* __restrict__ wth,
    u16* __restrict__ qkvb, u16* __restrict__ vg)
{
    __shared__ u16 Ab[32][512];   // (mt 0..7, s 0..3) 1KB subs : 32KB
    __shared__ u16 Bb[16][512];   // (nt 0..3, s 0..3)          : 16KB
    const int bn = blockIdx.x * 64;
    const int bm = blockIdx.y * 128;
    const int tid = threadIdx.x;
    const int wv = tid >> 6, lane = tid & 63;
    const int lr = lane & 15, quad = lane >> 4;
    const int lo = lane & 15, hi = lane >> 4;

    // stage A(128x128) + B(64x128): 48 x 1KB wave-insts, 12 per wave
    #pragma unroll
    for (int i = 0; i < 12; ++i) {
        const int idx = wv * 12 + i;
        if (idx < 32) {
            const int mt = idx >> 2, s = idx & 3;
            gload_lds16(xh + (size_t)(bm + mt * 16 + lo) * DIM_ + s * 32 + hi * 8,
                        &Ab[idx][0]);
        } else {
            const int j = idx - 32, nt = j >> 2, s = j & 3;
            gload_lds16(wth + (size_t)(bn + nt * 16 + lo) * DIM_ + s * 32 + hi * 8,
                        &Bb[j][0]);
        }
    }
    __syncthreads();

    // wave quadrant: wr selects 64 rows (4 m-tiles), wc selects 32 cols (2 n-tiles)
    const int wr = wv >> 1, wc = wv & 1;
    f32x4 acc[4][2] = {};
    #pragma unroll
    for (int s = 0; s < 4; ++s) {
        short8 af[4], bf[2];
        #pragma unroll
        for (int mt = 0; mt < 4; ++mt)
            af[mt] = *(const short8*)&Ab[(wr * 4 + mt) * 4 + s][lane * 8];
        #pragma unroll
        for (int nt = 0; nt < 2; ++nt)
            bf[nt] = *(const short8*)&Bb[(wc * 2 + nt) * 4 + s][lane * 8];
        #pragma unroll
        for (int mt = 0; mt < 4; ++mt)
            #pragma unroll
            for (int nt = 0; nt < 2; ++nt)
                acc[mt][nt] = MFMA16(af[mt], bf[nt], acc[mt][nt], 0, 0, 0);
    }

    if (bn < 2560) {
        #pragma unroll
        for (int mt = 0; mt < 4; ++mt)
            #pragma unroll
            for (int nt = 0; nt < 2; ++nt)
                #pragma unroll
                for (int r = 0; r < 4; ++r)
                    qkvb[(size_t)(bm + wr * 64 + mt * 16 + quad * 4 + r) * QKV_LD
                         + bn + wc * 32 + nt * 16 + lr] = f2bf(acc[mt][nt][r]);
    } else {
        #pragma unroll
        for (int mt = 0; mt < 4; ++mt)
            #pragma unroll
            for (int nt = 0; nt < 2; ++nt) {
                const int ncol = bn + wc * 32 + nt * 16 + lr - 2560;
                const int kvh = ncol >> 7, d = ncol & 127;
                #pragma unroll
                for (int r = 0; r < 4; ++r) {
                    const int m = bm + wr * 64 + mt * 16 + quad * 4 + r;
                    vg[((size_t)((m >> 11) * KVH_ + kvh) * DIM_ + d) * SEQ_
                       + (m & 2047)] = f2bf(acc[mt][nt][r]);
                }
            }
    }
}

// ---------- Attention: block = (b, kvh, 32-query tile), wave = head --------
// K/V 32-key chunks staged in LDS (double-buffered, identity frag layout),
// shared by the 4 heads of the GQA group. Fixed-shift exp2 softmax, O in regs.
__global__ __launch_bounds__(256) void attn_mfma(
    const u16* __restrict__ qkvb, const u16* __restrict__ vg,
    u16* __restrict__ ah)
{
    const int qb = blockIdx.x, kvh = blockIdx.y, b = blockIdx.z;
    const int q0 = qb << 5;
    const int tid = threadIdx.x;
    const int wv = tid >> 6, lane = tid & 63;
    const int lr = lane & 15, quad = lane >> 4;
    const int h = kvh * 4 + wv;                 // wave's q-head

    __shared__ u16 Kb[2][8][512];   // [buf][nt*4+s][slot] 16KB
    __shared__ u16 Vb[2][8][512];   // [buf][nt][slot]     16KB
    __shared__ u16 Pb[4][1024];     // per-wave [32 rows][32 keys] 8KB

    const float scale2 = 0.08838834764831845f * 1.4426950408889634f;
    const float slope2 = exp2f(-0.5f * (float)(h + 1)) * 1.4426950408889634f;
    const int jbase = max(0, q0 - WIN_);
    const int nch = (q0 + 32 - jbase) >> 5;     // chunks of 32 keys
    const size_t rowb = (size_t)b * SEQ_;
    const u16* kg = qkvb + rowb * QKV_LD + (QH_ + kvh) * DIM_;   // + key*QKV_LD
    const u16* vgb = vg + (size_t)(b * KVH_ + kvh) * DIM_ * SEQ_; // + d*SEQ

    // Q A-frags: qf[mt][s], rows q0+mt*16+lr, dims s*32+quad*8
    short8 qf[2][4];
    #pragma unroll
    for (int mt = 0; mt < 2; ++mt) {
        const u16* qp = qkvb + (rowb + q0 + mt * 16 + lr) * QKV_LD
                        + h * DIM_ + quad * 8;
        #pragma unroll
        for (int s = 0; s < 4; ++s) qf[mt][s] = *(const short8*)(qp + 32 * s);
    }

    f32x4 O[2][8] = {};
    float rs[2][4] = {};

    const int lo = lane & 15, hi = lane >> 4;
    // stage chunk 0 into buf 0
    {
        const int jk = jbase;
        #pragma unroll
        for (int t = 0; t < 2; ++t) {
            const int p = wv + t * 4;                    // K sub: nt=p>>2, s=p&3
            gload_lds16(kg + (size_t)(jk + (p >> 2) * 16 + lo) * QKV_LD
                        + (p & 3) * 32 + hi * 8, &Kb[0][p][0]);
            gload_lds16(vgb + (size_t)(p * 16 + lo) * SEQ_ + jk + hi * 8,
                        &Vb[0][p][0]);                    // V sub nt=p
        }
    }

    int buf = 0;
    for (int ch = 0; ch < nch; ++ch, buf ^= 1) {
        const int jk = jbase + (ch << 5);
        __syncthreads();                                  // stage(ch) done
        if (ch + 1 < nch) {                               // prefetch ch+1
            const int jn = jk + 32;
            #pragma unroll
            for (int t = 0; t < 2; ++t) {
                const int p = wv + t * 4;
                gload_lds16(kg + (size_t)(jn + (p >> 2) * 16 + lo) * QKV_LD
                            + (p & 3) * 32 + hi * 8, &Kb[buf ^ 1][p][0]);
                gload_lds16(vgb + (size_t)(p * 16 + lo) * SEQ_ + jn + hi * 8,
                            &Vb[buf ^ 1][p][0]);
            }
        }

        // QK^T for this wave's head: 2 m-tiles x 2 n-tiles x 4 k-slices
        #pragma unroll
        for (int nt = 0; nt < 2; ++nt) {
            f32x4 c0 = {0.f, 0.f, 0.f, 0.f}, c1 = {0.f, 0.f, 0.f, 0.f};
            #pragma unroll
            for (int s = 0; s < 4; ++s) {
                short8 kf = *(const short8*)&Kb[buf][nt * 4 + s][lane * 8];
                c0 = MFMA16(qf[0][s], kf, c0, 0, 0, 0);
                c1 = MFMA16(qf[1][s], kf, c1, 0, 0, 0);
            }
            const int j = jk + nt * 16 + lr;
            #pragma unroll
            for (int mt = 0; mt < 2; ++mt) {
                const f32x4 c = mt ? c1 : c0;
                #pragma unroll
                for (int r = 0; r < 4; ++r) {
                    const int q = q0 + mt * 16 + quad * 4 + r;
                    const int rel = q - j;
                    const int relmax = (q < WIN_) ? q : WIN_;
                    float e = 0.f;
                    if (rel >= 0 && rel <= WIN_)
                        e = exp2f(fmaf(c[r], scale2,
                                       slope2 * (float)(rel - relmax)));
                    rs[mt][r] += e;
                    Pb[wv][(mt * 16 + quad * 4 + r) * 32 + nt * 16 + lr] = f2bf(e);
                }
            }
        }
        // intra-wave LDS visibility for the P transpose (no block barrier)
        __asm__ volatile("s_waitcnt lgkmcnt(0)" ::: "memory");

        short8 pa0 = *(const short8*)&Pb[wv][(lr) * 32 + quad * 8];
        short8 pa1 = *(const short8*)&Pb[wv][(16 + lr) * 32 + quad * 8];
        #pragma unroll
        for (int nt = 0; nt < 8; ++nt) {
            short8 vf = *(const short8*)&Vb[buf][nt][lane * 8];
            O[0][nt] = MFMA16(pa0, vf, O[0][nt], 0, 0, 0);
            O[1][nt] = MFMA16(pa1, vf, O[1][nt], 0, 0, 0);
        }
    }

    // row-sum reduce over lr (16-lane groups share rows)
    #pragma unroll
    for (int o = 1; o < 16; o <<= 1)
        #pragma unroll
        for (int mt = 0; mt < 2; ++mt)
            #pragma unroll
            for (int r = 0; r < 4; ++r)
                rs[mt][r] += __shfl_xor(rs[mt][r], o, 16);

    #pragma unroll
    for (int mt = 0; mt < 2; ++mt) {
        float inv[4];
        #pragma unroll
        for (int r = 0; r < 4; ++r) inv[r] = 1.0f / rs[mt][r];
        #pragma unroll
        for (int nt = 0; nt < 8; ++nt)
            #pragma unroll
            for (int r = 0; r < 4; ++r)
                ah[(rowb + q0 + mt * 16 + quad * 4 + r) * (size_t)ATT_LD
                   + h * DIM_ + nt * 16 + lr] = f2bf(O[mt][nt][r] * inv[r]);
    }
}

// ---------- GEMM2 (MFMA): out = att @ Wproj, A bf16, B split bf16 ----------
// 512 threads: 8 waves = (mt 0..1) x (kh 0..3 K-quarters of 512); LDS combine.
__global__ __launch_bounds__(512) void gemm2_mfma(
    const u16* __restrict__ ah,
    const u16* __restrict__ wpth, const u16* __restrict__ wptl,
    float* __restrict__ out)
{
    __shared__ float Cp[3][2][16][128];   // 48KB partials from kh=1..3
    const int bm = blockIdx.x * 32;
    const int tid = threadIdx.x;
    const int wv = tid >> 6, lane = tid & 63;
    const int lr = lane & 15, quad = lane >> 4;
    const int mt = wv & 1, kh = wv >> 1;

    const u16* arow = ah + (size_t)(bm + mt * 16 + lr) * ATT_LD
                      + kh * 512 + quad * 8;
    f32x4 acc[8] = {};
    for (int it = 0; it < 8; ++it) {              // 64-k per iter
        const int k0 = it * 64;
        short8 a0 = *(const short8*)(arow + k0);
        short8 a1 = *(const short8*)(arow + k0 + 32);
        #pragma unroll
        for (int nt = 0; nt < 8; ++nt) {
            const size_t bofs = (size_t)(nt * 16 + lr) * ATT_LD + kh * 512 + k0
                                + quad * 8;
            short8 b0h = *(const short8*)(wpth + bofs);
            short8 b0l = *(const short8*)(wptl + bofs);
            short8 b1h = *(const short8*)(wpth + bofs + 32);
            short8 b1l = *(const short8*)(wptl + bofs + 32);
            acc[nt] = MFMA16(a0, b0h, acc[nt], 0, 0, 0);
            acc[nt] = MFMA16(a0, b0l, acc[nt], 0, 0, 0);
            acc[nt] = MFMA16(a1, b1h, acc[nt], 0, 0, 0);
            acc[nt] = MFMA16(a1, b1l, acc[nt], 0, 0, 0);
        }
    }

    if (kh > 0) {
        #pragma unroll
        for (int nt = 0; nt < 8; ++nt)
            #pragma unroll
            for (int r = 0; r < 4; ++r)
                Cp[kh - 1][mt][quad * 4 + r][nt * 16 + lr] = acc[nt][r];
    }
    __syncthreads();
    if (kh == 0) {
        #pragma unroll
        for (int nt = 0; nt < 8; ++nt)
            #pragma unroll
            for (int r = 0; r < 4; ++r) {
                const int rr = quad * 4 + r, cc = nt * 16 + lr;
                out[(size_t)(bm + mt * 16 + rr) * DIM_ + cc] =
                    acc[nt][r] + Cp[0][mt][rr][cc] + Cp[1][mt][rr][cc]
                    + Cp[2][mt][rr][cc];
            }
    }
}

// ---------- launch ----------------------------------------------------------
extern "C" void kernel_launch(void* const* d_in, const int* in_sizes, int n_in,
                              void* d_out, int out_size, void* d_ws, size_t ws_size,
                              hipStream_t stream)
{
    const float* x     = (const float*)d_in[0];
    const float* Wqkv  = (const float*)d_in[1];
    const float* Wproj = (const float*)d_in[2];
    float* out = (float*)d_out;

    u16* xh   = (u16*)d_ws;
    u16* wth  = xh   + (size_t)NX;
    u16* wpth = wth  + (size_t)NWQ;
    u16* wptl = wpth + (size_t)NWP;
    u16* qkvb = wptl + (size_t)NWP;                         // 8192*3072
    u16* vg   = qkvb + (size_t)8192 * QKV_LD;               // 4*4*128*2048
    u16* ahp  = vg   + (size_t)BATCH_ * KVH_ * DIM_ * SEQ_; // 8192*2048

    convert_inputs<<<(NX + NWQ + NWP) / 256, 256, 0, stream>>>(
        x, Wqkv, Wproj, xh, wth, wpth, wptl);

    gemm1_mfma<<<dim3(QKV_LD / 64, 8192 / 128), 256, 0, stream>>>(
        xh, wth, qkvb, vg);

    attn_mfma<<<dim3(SEQ_ / 32, KVH_, BATCH_), 256, 0, stream>>>(qkvb, vg, ahp);

    gemm2_mfma<<<8192 / 32, 512, 0, stream>>>(ahp, wpth, wptl, out);
}

// Round 6
// 228.247 us; speedup vs baseline: 2.2585x; 1.0536x over previous
//
#include <hip/hip_runtime.h>
#include <math.h>

#define DIM_    128
#define QH_     16
#define KVH_    4
#define WIN_    512
#define BATCH_  4
#define SEQ_    2048
#define QKV_LD  3072
#define ATT_LD  2048

#define NX   (BATCH_*SEQ_*DIM_)   // 1048576
#define NWQ  (DIM_*QKV_LD)        // 393216
#define NWP  (ATT_LD*DIM_)        // 262144

typedef __attribute__((ext_vector_type(8))) short short8;
typedef __attribute__((ext_vector_type(4))) float f32x4;
typedef unsigned short u16;
typedef unsigned int u32;

__device__ __forceinline__ u16 f2bf(float f) {
    u32 u = __float_as_uint(f);
    u += 0x7fff + ((u >> 16) & 1);
    return (u16)(u >> 16);
}
__device__ __forceinline__ float bf2f(u16 u) {
    return __uint_as_float(((u32)u) << 16);
}
#define MFMA16 __builtin_amdgcn_mfma_f32_16x16x32_bf16

__device__ __forceinline__ void gload_lds16(const u16* g, u16* l) {
    __builtin_amdgcn_global_load_lds(
        (const __attribute__((address_space(1))) unsigned int*)(const void*)g,
        (__attribute__((address_space(3))) unsigned int*)(void*)l, 16, 0, 0);
}

// ---------- convert: xh = bf16(x); wth = bf16(Wqkv^T)[3072][128];
//            wpth = bf16(Wproj^T)[128][2048]
__global__ __launch_bounds__(256) void convert_inputs(
    const float* __restrict__ x, const float* __restrict__ Wqkv,
    const float* __restrict__ Wproj,
    u16* __restrict__ xh, u16* __restrict__ wth, u16* __restrict__ wpth)
{
    const int t = blockIdx.x * 256 + threadIdx.x;
    if (t < NX) {
        xh[t] = f2bf(x[t]);
    } else if (t < NX + NWQ) {
        const int u2 = t - NX;
        const int k = u2 & 127, n = u2 >> 7;
        wth[u2] = f2bf(Wqkv[(size_t)k * QKV_LD + n]);
    } else {
        const int u2 = t - NX - NWQ;
        const int k = u2 & 2047, n = u2 >> 11;
        wpth[u2] = f2bf(Wproj[(size_t)k * DIM_ + n]);
    }
}

// ---------- GEMM1 (bf16 MFMA, LDS-tiled): qkv = x @ Wqkv -------------------
// Block 128(M) x 64(N), K=128 one-shot. Q/K region computed TRANSPOSED
// (swap MFMA operands) so output cols land in consecutive regs -> ushort4
// stores into row-major qkvb. V region keeps normal orientation: consecutive
// regs = consecutive seq -> ushort4 into vg[b][kvh][d][seq].
__global__ __launch_bounds__(256) void gemm1_mfma(
    const u16* __restrict__ xh, const u16* __restrict__ wth,
    u16* __restrict__ qkvb, u16* __restrict__ vg)
{
    __shared__ u16 Ab[32][512];   // x tiles   32KB
    __shared__ u16 Bb[16][512];   // w tiles   16KB
    const int bn = blockIdx.x * 64;
    const int bm = blockIdx.y * 128;
    const int tid = threadIdx.x;
    const int wv = tid >> 6, lane = tid & 63;
    const int lr = lane & 15, quad = lane >> 4;
    const int lo = lane & 15, hi = lane >> 4;

    #pragma unroll
    for (int i = 0; i < 12; ++i) {
        const int idx = wv * 12 + i;
        if (idx < 32) {
            const int mt = idx >> 2, s = idx & 3;
            gload_lds16(xh + (size_t)(bm + mt * 16 + lo) * DIM_ + s * 32 + hi * 8,
                        &Ab[idx][0]);
        } else {
            const int j = idx - 32, nt = j >> 2, s = j & 3;
            gload_lds16(wth + (size_t)(bn + nt * 16 + lo) * DIM_ + s * 32 + hi * 8,
                        &Bb[j][0]);
        }
    }
    __syncthreads();

    const int wr = wv >> 1, wc = wv & 1;
    f32x4 acc[4][2] = {};
    if (bn < 2560) {                       // TRANSPOSED: A=w, B=x
        #pragma unroll
        for (int s = 0; s < 4; ++s) {
            short8 af[4], bf[2];
            #pragma unroll
            for (int mt = 0; mt < 4; ++mt)
                af[mt] = *(const short8*)&Ab[(wr * 4 + mt) * 4 + s][lane * 8];
            #pragma unroll
            for (int nt = 0; nt < 2; ++nt)
                bf[nt] = *(const short8*)&Bb[(wc * 2 + nt) * 4 + s][lane * 8];
            #pragma unroll
            for (int mt = 0; mt < 4; ++mt)
                #pragma unroll
                for (int nt = 0; nt < 2; ++nt)
                    acc[mt][nt] = MFMA16(bf[nt], af[mt], acc[mt][nt], 0, 0, 0);
        }
        #pragma unroll
        for (int mt = 0; mt < 4; ++mt)
            #pragma unroll
            for (int nt = 0; nt < 2; ++nt) {
                ushort4 o;
                o.x = f2bf(acc[mt][nt][0]); o.y = f2bf(acc[mt][nt][1]);
                o.z = f2bf(acc[mt][nt][2]); o.w = f2bf(acc[mt][nt][3]);
                *(ushort4*)(qkvb
                    + (size_t)(bm + wr * 64 + mt * 16 + lr) * QKV_LD
                    + bn + wc * 32 + nt * 16 + quad * 4) = o;
            }
    } else {                               // normal: A=x, B=w
        #pragma unroll
        for (int s = 0; s < 4; ++s) {
            short8 af[4], bf[2];
            #pragma unroll
            for (int mt = 0; mt < 4; ++mt)
                af[mt] = *(const short8*)&Ab[(wr * 4 + mt) * 4 + s][lane * 8];
            #pragma unroll
            for (int nt = 0; nt < 2; ++nt)
                bf[nt] = *(const short8*)&Bb[(wc * 2 + nt) * 4 + s][lane * 8];
            #pragma unroll
            for (int mt = 0; mt < 4; ++mt)
                #pragma unroll
                for (int nt = 0; nt < 2; ++nt)
                    acc[mt][nt] = MFMA16(af[mt], bf[nt], acc[mt][nt], 0, 0, 0);
        }
        #pragma unroll
        for (int mt = 0; mt < 4; ++mt)
            #pragma unroll
            for (int nt = 0; nt < 2; ++nt) {
                const int ncol = bn + wc * 32 + nt * 16 + lr - 2560;
                const int kvh = ncol >> 7, d = ncol & 127;
                const int m0 = bm + wr * 64 + mt * 16 + quad * 4;
                ushort4 o;
                o.x = f2bf(acc[mt][nt][0]); o.y = f2bf(acc[mt][nt][1]);
                o.z = f2bf(acc[mt][nt][2]); o.w = f2bf(acc[mt][nt][3]);
                *(ushort4*)(vg + ((size_t)((m0 >> 11) * KVH_ + kvh) * DIM_ + d)
                            * SEQ_ + (m0 & 2047)) = o;
            }
    }
}

// ---------- Attention: block = (b, kvh, 64-q tile), 512 thr = 8 waves ------
// wave = (head 0..3) x (m-half 0..1); K/V 32-key chunks staged in LDS shared
// by 8 waves. PV uses swapped operands (O^T): q = lane col, d = regs ->
// ushort4 epilogue stores. Per-wave chunk-range skip removes masked chunks.
__global__ __launch_bounds__(512) void attn_mfma(
    const u16* __restrict__ qkvb, const u16* __restrict__ vg,
    u16* __restrict__ ah)
{
    const int qb = blockIdx.x, kvh = blockIdx.y, b = blockIdx.z;
    const int q0 = qb << 6;
    const int tid = threadIdx.x;
    const int wv = tid >> 6, lane = tid & 63;
    const int lr = lane & 15, quad = lane >> 4;
    const int hl = wv & 3, mh = wv >> 2;
    const int h = kvh * 4 + hl;
    const int qw = q0 + mh * 32;                // wave's first query

    __shared__ u16 Kb[2][8][512];   // 16KB
    __shared__ u16 Vb[2][8][512];   // 16KB
    __shared__ u16 Pb[8][1024];     // 16KB  per-wave 32x32 P
    __shared__ float Sm[8][32];     // row sums per wave

    const float scale2 = 0.08838834764831845f * 1.4426950408889634f;
    const float slope2 = exp2f(-0.5f * (float)(h + 1)) * 1.4426950408889634f;
    const int jbase = max(0, q0 - WIN_);
    const int nch = (q0 + 64 - jbase) >> 5;
    const int c_lo = (qw - WIN_ > jbase) ? ((qw - WIN_ - jbase) >> 5) : 0;
    const int c_hi = (qw + 32 - jbase) >> 5;
    const size_t rowb = (size_t)b * SEQ_;
    const u16* kg  = qkvb + rowb * QKV_LD + (QH_ + kvh) * DIM_;
    const u16* vgb = vg + (size_t)(b * KVH_ + kvh) * DIM_ * SEQ_;

    short8 qf[2][4];
    #pragma unroll
    for (int mt = 0; mt < 2; ++mt) {
        const u16* qp = qkvb + (rowb + qw + mt * 16 + lr) * QKV_LD
                        + h * DIM_ + quad * 8;
        #pragma unroll
        for (int s = 0; s < 4; ++s) qf[mt][s] = *(const short8*)(qp + 32 * s);
    }

    f32x4 O[2][8] = {};            // O^T: [mt][nt], rows d=quad*4+r, col q=lr
    float rs[2][4] = {};
    const int lo = lane & 15, hi = lane >> 4;

    // stage chunk 0 (each wave: 1 K-sub + 1 V-sub)
    gload_lds16(kg + (size_t)(jbase + (wv >> 2) * 16 + lo) * QKV_LD
                + (wv & 3) * 32 + hi * 8, &Kb[0][wv][0]);
    gload_lds16(vgb + (size_t)(wv * 16 + lo) * SEQ_ + jbase + hi * 8,
                &Vb[0][wv][0]);

    int buf = 0;
    for (int ch = 0; ch < nch; ++ch, buf ^= 1) {
        const int jk = jbase + (ch << 5);
        __syncthreads();
        if (ch + 1 < nch) {
            const int jn = jk + 32;
            gload_lds16(kg + (size_t)(jn + (wv >> 2) * 16 + lo) * QKV_LD
                        + (wv & 3) * 32 + hi * 8, &Kb[buf ^ 1][wv][0]);
            gload_lds16(vgb + (size_t)(wv * 16 + lo) * SEQ_ + jn + hi * 8,
                        &Vb[buf ^ 1][wv][0]);
        }
        if (ch < c_lo || ch >= c_hi) continue;   // wave-uniform skip

        #pragma unroll
        for (int nt = 0; nt < 2; ++nt) {
            f32x4 c0 = {0.f, 0.f, 0.f, 0.f}, c1 = {0.f, 0.f, 0.f, 0.f};
            #pragma unroll
            for (int s = 0; s < 4; ++s) {
                short8 kf = *(const short8*)&Kb[buf][nt * 4 + s][lane * 8];
                c0 = MFMA16(qf[0][s], kf, c0, 0, 0, 0);
                c1 = MFMA16(qf[1][s], kf, c1, 0, 0, 0);
            }
            const int j = jk + nt * 16 + lr;
            #pragma unroll
            for (int mt = 0; mt < 2; ++mt) {
                const f32x4 c = mt ? c1 : c0;
                #pragma unroll
                for (int r = 0; r < 4; ++r) {
                    const int q = qw + mt * 16 + quad * 4 + r;
                    const int rel = q - j;
                    const int relmax = (q < WIN_) ? q : WIN_;
                    float e = 0.f;
                    if (rel >= 0 && rel <= WIN_)
                        e = exp2f(fmaf(c[r], scale2,
                                       slope2 * (float)(rel - relmax)));
                    rs[mt][r] += e;
                    Pb[wv][(mt * 16 + quad * 4 + r) * 32 + nt * 16 + lr] = f2bf(e);
                }
            }
        }
        __asm__ volatile("s_waitcnt lgkmcnt(0)" ::: "memory");

        short8 pa0 = *(const short8*)&Pb[wv][(lr) * 32 + quad * 8];
        short8 pa1 = *(const short8*)&Pb[wv][(16 + lr) * 32 + quad * 8];
        #pragma unroll
        for (int nt = 0; nt < 8; ++nt) {
            short8 vf = *(const short8*)&Vb[buf][nt][lane * 8];
            O[0][nt] = MFMA16(vf, pa0, O[0][nt], 0, 0, 0);   // O^T
            O[1][nt] = MFMA16(vf, pa1, O[1][nt], 0, 0, 0);
        }
    }

    // row-sum reduce across lr groups, then redistribute via LDS (q = lr)
    #pragma unroll
    for (int o = 1; o < 16; o <<= 1)
        #pragma unroll
        for (int mt = 0; mt < 2; ++mt)
            #pragma unroll
            for (int r = 0; r < 4; ++r)
                rs[mt][r] += __shfl_xor(rs[mt][r], o, 16);
    if (lr == 0) {
        #pragma unroll
        for (int mt = 0; mt < 2; ++mt)
            #pragma unroll
            for (int r = 0; r < 4; ++r)
                Sm[wv][mt * 16 + quad * 4 + r] = rs[mt][r];
    }
    __asm__ volatile("s_waitcnt lgkmcnt(0)" ::: "memory");

    #pragma unroll
    for (int mt = 0; mt < 2; ++mt) {
        const float inv = 1.0f / Sm[wv][mt * 16 + lr];
        u16* dst = ah + (rowb + qw + mt * 16 + lr) * (size_t)ATT_LD + h * DIM_;
        #pragma unroll
        for (int nt = 0; nt < 8; ++nt) {
            ushort4 o;
            o.x = f2bf(O[mt][nt][0] * inv); o.y = f2bf(O[mt][nt][1] * inv);
            o.z = f2bf(O[mt][nt][2] * inv); o.w = f2bf(O[mt][nt][3] * inv);
            *(ushort4*)(dst + nt * 16 + quad * 4) = o;
        }
    }
}

// ---------- GEMM2 (bf16 MFMA, transposed): out = att @ Wproj ---------------
// 512 thr: 8 waves = (mt 0..1) x (kh 0..3 K-quarters); A=Wp^T rows (n),
// B=att rows (m) -> out cols in regs -> float4 stores; LDS split-K combine.
__global__ __launch_bounds__(512) void gemm2_mfma(
    const u16* __restrict__ ah, const u16* __restrict__ wpth,
    float* __restrict__ out)
{
    __shared__ float Cp[3][2][16][132];   // ~49.5KB partials kh=1..3
    const int bm = blockIdx.x * 32;
    const int tid = threadIdx.x;
    const int wv = tid >> 6, lane = tid & 63;
    const int lr = lane & 15, quad = lane >> 4;
    const int mt = wv & 1, kh = wv >> 1;

    const u16* arow = ah + (size_t)(bm + mt * 16 + lr) * ATT_LD
                      + kh * 512 + quad * 8;
    f32x4 acc[8] = {};
    for (int it = 0; it < 8; ++it) {
        const int k0 = it * 64;
        short8 at0 = *(const short8*)(arow + k0);
        short8 at1 = *(const short8*)(arow + k0 + 32);
        #pragma unroll
        for (int nt = 0; nt < 8; ++nt) {
            const size_t bofs = (size_t)(nt * 16 + lr) * ATT_LD + kh * 512 + k0
                                + quad * 8;
            short8 w0 = *(const short8*)(wpth + bofs);
            short8 w1 = *(const short8*)(wpth + bofs + 32);
            acc[nt] = MFMA16(w0, at0, acc[nt], 0, 0, 0);   // transposed
            acc[nt] = MFMA16(w1, at1, acc[nt], 0, 0, 0);
        }
    }

    if (kh > 0) {
        #pragma unroll
        for (int nt = 0; nt < 8; ++nt)
            *(f32x4*)&Cp[kh - 1][mt][lr][nt * 16 + quad * 4] = acc[nt];
    }
    __syncthreads();
    if (kh == 0) {
        #pragma unroll
        for (int nt = 0; nt < 8; ++nt) {
            const int cc = nt * 16 + quad * 4;
            f32x4 s = acc[nt];
            f32x4 p0 = *(const f32x4*)&Cp[0][mt][lr][cc];
            f32x4 p1 = *(const f32x4*)&Cp[1][mt][lr][cc];
            f32x4 p2 = *(const f32x4*)&Cp[2][mt][lr][cc];
            float4 o = make_float4(s[0] + p0[0] + p1[0] + p2[0],
                                   s[1] + p0[1] + p1[1] + p2[1],
                                   s[2] + p0[2] + p1[2] + p2[2],
                                   s[3] + p0[3] + p1[3] + p2[3]);
            *(float4*)(out + (size_t)(bm + mt * 16 + lr) * DIM_ + cc) = o;
        }
    }
}

// ---------- launch ----------------------------------------------------------
extern "C" void kernel_launch(void* const* d_in, const int* in_sizes, int n_in,
                              void* d_out, int out_size, void* d_ws, size_t ws_size,
                              hipStream_t stream)
{
    const float* x     = (const float*)d_in[0];
    const float* Wqkv  = (const float*)d_in[1];
    const float* Wproj = (const float*)d_in[2];
    float* out = (float*)d_out;

    u16* xh   = (u16*)d_ws;
    u16* wth  = xh   + (size_t)NX;
    u16* wpth = wth  + (size_t)NWQ;
    u16* qkvb = wpth + (size_t)NWP;                         // 8192*3072
    u16* vg   = qkvb + (size_t)8192 * QKV_LD;               // 4*4*128*2048
    u16* ahp  = vg   + (size_t)BATCH_ * KVH_ * DIM_ * SEQ_; // 8192*2048

    convert_inputs<<<(NX + NWQ + NWP) / 256, 256, 0, stream>>>(
        x, Wqkv, Wproj, xh, wth, wpth);

    gemm1_mfma<<<dim3(QKV_LD / 64, 8192 / 128), 256, 0, stream>>>(
        xh, wth, qkvb, vg);

    attn_mfma<<<dim3(SEQ_ / 64, KVH_, BATCH_), 512, 0, stream>>>(qkvb, vg, ahp);

    gemm2_mfma<<<8192 / 32, 512, 0, stream>>>(ahp, wpth, out);
}